// Round 2
// baseline (322.367 us; speedup 1.0000x reference)
//
#include <hip/hip_runtime.h>
#include <hip/hip_bf16.h>
#include <stdint.h>

#define SEQ 4096
#define BATCH 16
#define HID 512
#define ATT_OFF (BATCH * HID)                 // 8192  elements into d_out
#define NSS_OFF (BATCH * HID + BATCH * SEQ)   // 73728 elements into d_out
#define SPB 16                                // s per block in stream kernels
#define NCHUNK (SEQ / SPB)                    // 256 chunks per batch
#define SPW (SPB / 4)                         // 4 s per wave  (spill-proof tile)

typedef unsigned short u16;
typedef unsigned int u32;

__device__ __forceinline__ float bflo(u32 w) { return __uint_as_float(w << 16); }
__device__ __forceinline__ float bfhi(u32 w) { return __uint_as_float(w & 0xffff0000u); }

__device__ __forceinline__ u16 f2bf(float f) {  // round-to-nearest-even
  u32 u = __float_as_uint(f);
  return (u16)((u + 0x7fffu + ((u >> 16) & 1u)) >> 16);
}

// Runtime dtype probe (insurance; prior sessions proved fp32).
__device__ __forceinline__ int probe_bf16(const void* tssp) {
  const u16* t = (const u16*)tssp;
  int ok = 1;
  #pragma unroll
  for (int i = 0; i < 8; i += 2) {
    u16 u = t[i];
    ok &= (u >= 0x3F00 && u <= 0x3FC0) ? 1 : 0;
  }
  return ok;
}

template <int BF>
__device__ __forceinline__ float ld1(const void* p, size_t i) {
  if (BF) return __uint_as_float(((u32)((const u16*)p)[i]) << 16);
  return ((const float*)p)[i];
}

template <int BF>
__device__ __forceinline__ void st1(void* p, size_t i, float v) {
  if (BF) ((u16*)p)[i] = f2bf(v);
  else    ((float*)p)[i] = v;
}

template <int BF>
__device__ __forceinline__ void load8(const void* p, size_t e, float* o) {
  if (BF) {
    uint4 v = *(const uint4*)((const u16*)p + e);
    o[0]=bflo(v.x); o[1]=bfhi(v.x); o[2]=bflo(v.y); o[3]=bfhi(v.y);
    o[4]=bflo(v.z); o[5]=bfhi(v.z); o[6]=bflo(v.w); o[7]=bfhi(v.w);
  } else {
    const float4* f = (const float4*)((const float*)p + e);
    float4 a = f[0], b = f[1];
    o[0]=a.x; o[1]=a.y; o[2]=a.z; o[3]=a.w;
    o[4]=b.x; o[5]=b.y; o[6]=b.z; o[7]=b.w;
  }
}

__device__ __forceinline__ float fast_tanh(float x) {
  float e = __expf(2.0f * x);
  return 1.0f - 2.0f * __builtin_amdgcn_rcpf(e + 1.0f);
}

// ---------- K1: dec[b,k] = sum_h oh[b,h]*W[k,h] + bias[k] ----------
template <int BF>
__device__ __forceinline__ void k_dec_body(
    const void* oh, const void* W, const void* bias, float* dec) {
  int tid = threadIdx.x;
  int gw = blockIdx.x * 4 + (tid >> 6);   // 8192 waves = 16 b * 512 k
  int lane = tid & 63;
  int k = gw & (HID - 1);
  int b = gw >> 9;
  float wv[8], ov[8];
  load8<BF>(W,  (size_t)k * HID + lane * 8, wv);
  load8<BF>(oh, (size_t)b * HID + lane * 8, ov);
  float acc = 0.0f;
  #pragma unroll
  for (int j = 0; j < 8; ++j) acc += wv[j] * ov[j];
  #pragma unroll
  for (int off = 32; off; off >>= 1) acc += __shfl_xor(acc, off, 64);
  if (lane == 0) dec[b * HID + k] = acc + ld1<BF>(bias, k);
}

__global__ __launch_bounds__(256) void k_dec(
    const void* oh, const void* W, const void* bias, const void* tss,
    float* dec, float* denom) {
  if (blockIdx.x == 0 && threadIdx.x < BATCH) denom[threadIdx.x] = 0.0f;
  if (probe_bf16(tss)) k_dec_body<1>(oh, W, bias, dec);
  else                 k_dec_body<0>(oh, W, bias, dec);
}

// ---------- K2: scores (streams ef only) ----------
// 4096 blocks = 256 chunks * 16 b (b-fast); wave owns 4 consecutive s rows.
// ev[4][8] = 32 data VGPRs -> total ~75 regs, far under the 128 cap from
// __launch_bounds__(256,4): spill-impossible by construction. 8 dwordx4
// issued back-to-back per wave before any dependent compute.
template <int BF>
__device__ __forceinline__ void k_scores_body(
    const void* ef, const void* maskp, const void* tssp, const void* vp,
    const float* dec, float* w_buf, float* denom, void* out) {
  int tid = threadIdx.x, lane = tid & 63, wave = tid >> 6;
  int blk = blockIdx.x;
  int b = blk & (BATCH - 1);
  int chunk = blk >> 4;
  int s0 = chunk * SPB + wave * SPW;

  float ev[SPW][8];
  #pragma unroll
  for (int i = 0; i < SPW; ++i)
    load8<BF>(ef, ((size_t)(s0 + i) * BATCH + b) * HID + lane * 8, ev[i]);

  float dv[8], vv[8];
  #pragma unroll
  for (int j = 0; j < 8; ++j) dv[j] = dec[b * HID + lane * 8 + j];
  load8<BF>(vp, lane * 8, vv);

  float acc[SPW];
  #pragma unroll
  for (int i = 0; i < SPW; ++i) {
    float s = 0.0f;
    #pragma unroll
    for (int j = 0; j < 8; ++j) s += fast_tanh(ev[i][j] + dv[j]) * vv[j];
    acc[i] = s;
  }
  // Batched butterfly: 6 stages x 4 independent values.
  #pragma unroll
  for (int off = 32; off; off >>= 1) {
    #pragma unroll
    for (int i = 0; i < SPW; ++i) acc[i] += __shfl_xor(acc[i], off, 64);
  }
  // Per-s scalars; all lanes compute redundantly (uniform loads broadcast).
  float wsum = 0.0f;
  #pragma unroll
  for (int i = 0; i < SPW; ++i) {
    int s = s0 + i;
    float p  = __expf(acc[i]);
    float ts = ld1<BF>(tssp,  b * SEQ + s);
    float m  = ld1<BF>(maskp, b * SEQ + s);
    float wv = p * m * __builtin_amdgcn_rcpf(ts);
    wsum += wv;
    if (lane == 0) {
      st1<BF>(out, NSS_OFF + b * SEQ + s, p + ts);
      w_buf[b * SEQ + s] = wv;
    }
  }
  __shared__ float wpart[4];
  if (lane == 0) wpart[wave] = wsum;
  __syncthreads();
  if (tid == 0)
    atomicAdd(&denom[b], wpart[0] + wpart[1] + wpart[2] + wpart[3]);
}

__global__ __launch_bounds__(256, 4) void k_scores(
    const void* ef, const void* maskp, const void* tssp, const void* vp,
    const float* dec, float* w_buf, float* denom, void* out) {
  if (probe_bf16(tssp))
    k_scores_body<1>(ef, maskp, tssp, vp, dec, w_buf, denom, out);
  else
    k_scores_body<0>(ef, maskp, tssp, vp, dec, w_buf, denom, out);
}

// ---------- K3: context partials (streams eo only) ----------
// Same geometry as K2. eov[4][8] = 32 data regs, ~60 total: no spill risk.
template <int BF>
__device__ __forceinline__ void k_ctx_body(
    const void* eo, const float* w_buf, float* partial) {
  int tid = threadIdx.x, lane = tid & 63, wave = tid >> 6;
  int blk = blockIdx.x;
  int b = blk & (BATCH - 1);
  int chunk = blk >> 4;
  int s0 = chunk * SPB + wave * SPW;

  float eov[SPW][8];
  #pragma unroll
  for (int i = 0; i < SPW; ++i)
    load8<BF>(eo, ((size_t)(s0 + i) * BATCH + b) * HID + lane * 8, eov[i]);

  float w[SPW];
  #pragma unroll
  for (int i = 0; i < SPW; ++i) w[i] = w_buf[b * SEQ + s0 + i];

  float a[8] = {0,0,0,0,0,0,0,0};
  #pragma unroll
  for (int i = 0; i < SPW; ++i)
    #pragma unroll
    for (int j = 0; j < 8; ++j) a[j] += w[i] * eov[i][j];

  // Cross-wave reduce; lane-consecutive LDS layout -> conflict-free.
  __shared__ float red[3 * 8 * 64];
  if (wave > 0) {
    #pragma unroll
    for (int j = 0; j < 8; ++j) red[((wave - 1) * 8 + j) * 64 + lane] = a[j];
  }
  __syncthreads();
  if (wave == 0) {
    #pragma unroll
    for (int k = 0; k < 3; ++k)
      #pragma unroll
      for (int j = 0; j < 8; ++j) a[j] += red[(k * 8 + j) * 64 + lane];
    float4* p4 = (float4*)(partial + ((size_t)b * NCHUNK + chunk) * HID + lane * 8);
    p4[0] = make_float4(a[0], a[1], a[2], a[3]);
    p4[1] = make_float4(a[4], a[5], a[6], a[7]);
  }
}

__global__ __launch_bounds__(256, 4) void k_ctx(
    const void* eo, const void* tssp, const float* w_buf, float* partial) {
  if (probe_bf16(tssp)) k_ctx_body<1>(eo, w_buf, partial);
  else                  k_ctx_body<0>(eo, w_buf, partial);
}

// ---------- K4: finalize att and ctx ----------
// 512 blocks = 16 b * 32 parts. Per part: 128 s of att + 16 h of ctx.
// 256-chunk sum split across 16 lanes per h (16 loads each) + 4 shuffle
// stages.
template <int BF>
__device__ __forceinline__ void k_fin_body(
    const float* w_buf, const float* denom, const float* partial, void* out) {
  int b = blockIdx.x >> 5;
  int part = blockIdx.x & 31;
  int t = threadIdx.x;
  float inv_d = __builtin_amdgcn_rcpf(denom[b]);
  if (t < 128) {
    int s = part * 128 + t;
    st1<BF>(out, ATT_OFF + b * SEQ + s, w_buf[b * SEQ + s] * inv_d);
  }
  int hl = t >> 4, cp = t & 15;
  int h = part * 16 + hl;
  float sum = 0.0f;
  #pragma unroll
  for (int c = cp; c < NCHUNK; c += 16)
    sum += partial[((size_t)b * NCHUNK + c) * HID + h];
  #pragma unroll
  for (int off = 8; off; off >>= 1) sum += __shfl_xor(sum, off, 64);
  if (cp == 0) st1<BF>(out, b * HID + h, sum * inv_d);
}

__global__ __launch_bounds__(256) void k_finalize(
    const float* w_buf, const float* denom, const float* partial,
    const void* tssp, void* out) {
  if (probe_bf16(tssp)) k_fin_body<1>(w_buf, denom, partial, out);
  else                  k_fin_body<0>(w_buf, denom, partial, out);
}

extern "C" void kernel_launch(void* const* d_in, const int* in_sizes, int n_in,
                              void* d_out, int out_size, void* d_ws, size_t ws_size,
                              hipStream_t stream) {
  const void* oh   = d_in[0];
  const void* eo   = d_in[1];
  const void* ef   = d_in[2];
  const void* mask = d_in[3];
  const void* tss  = d_in[4];
  const void* W    = d_in[5];
  const void* bias = d_in[6];
  const void* v    = d_in[7];

  float* ws      = (float*)d_ws;
  float* dec     = ws;                    // 8192
  float* w_buf   = dec + BATCH * HID;     // 65536
  float* denom   = w_buf + BATCH * SEQ;   // 16
  float* partial = denom + 16;            // 16*256*512 = 2097152 (~8.3 MB total)

  k_dec     <<<2048, 256, 0, stream>>>(oh, W, bias, tss, dec, denom);
  k_scores  <<<4096, 256, 0, stream>>>(ef, mask, tss, v, dec, w_buf, denom, d_out);
  k_ctx     <<<4096, 256, 0, stream>>>(eo, tss, w_buf, partial);
  k_finalize<<< 512, 256, 0, stream>>>(w_buf, denom, partial, tss, d_out);
}

// Round 3
// 303.884 us; speedup vs baseline: 1.0608x; 1.0608x over previous
//
#include <hip/hip_runtime.h>
#include <hip/hip_bf16.h>
#include <stdint.h>

#define SEQ 4096
#define BATCH 16
#define HID 512
#define ATT_OFF (BATCH * HID)                 // 8192  elements into d_out
#define NSS_OFF (BATCH * HID + BATCH * SEQ)   // 73728 elements into d_out

// Stream-kernel geometry: wave owns 16 consecutive s as NT=4 tiles of SPW=4.
// Block = 4 waves = 64 consecutive s. Register-double-buffered across tiles.
#define SPW 4                                 // s rows per tile per wave
#define NT 4                                  // tiles per wave
#define SBLK (4 * NT * SPW)                   // 64 s per block
#define NGRP (SEQ / SBLK)                     // 64 groups per batch
#define NSTREAM_BLOCKS (BATCH * NGRP)         // 1024 blocks

typedef unsigned short u16;
typedef unsigned int u32;

__device__ __forceinline__ float bflo(u32 w) { return __uint_as_float(w << 16); }
__device__ __forceinline__ float bfhi(u32 w) { return __uint_as_float(w & 0xffff0000u); }

__device__ __forceinline__ u16 f2bf(float f) {  // round-to-nearest-even
  u32 u = __float_as_uint(f);
  return (u16)((u + 0x7fffu + ((u >> 16) & 1u)) >> 16);
}

// Runtime dtype probe (insurance; prior sessions proved fp32).
__device__ __forceinline__ int probe_bf16(const void* tssp) {
  const u16* t = (const u16*)tssp;
  int ok = 1;
  #pragma unroll
  for (int i = 0; i < 8; i += 2) {
    u16 u = t[i];
    ok &= (u >= 0x3F00 && u <= 0x3FC0) ? 1 : 0;
  }
  return ok;
}

template <int BF>
__device__ __forceinline__ float ld1(const void* p, size_t i) {
  if (BF) return __uint_as_float(((u32)((const u16*)p)[i]) << 16);
  return ((const float*)p)[i];
}

template <int BF>
__device__ __forceinline__ void st1(void* p, size_t i, float v) {
  if (BF) ((u16*)p)[i] = f2bf(v);
  else    ((float*)p)[i] = v;
}

template <int BF>
__device__ __forceinline__ void load8(const void* p, size_t e, float* o) {
  if (BF) {
    uint4 v = *(const uint4*)((const u16*)p + e);
    o[0]=bflo(v.x); o[1]=bfhi(v.x); o[2]=bflo(v.y); o[3]=bfhi(v.y);
    o[4]=bflo(v.z); o[5]=bfhi(v.z); o[6]=bflo(v.w); o[7]=bfhi(v.w);
  } else {
    const float4* f = (const float4*)((const float*)p + e);
    float4 a = f[0], b = f[1];
    o[0]=a.x; o[1]=a.y; o[2]=a.z; o[3]=a.w;
    o[4]=b.x; o[5]=b.y; o[6]=b.z; o[7]=b.w;
  }
}

__device__ __forceinline__ float fast_tanh(float x) {
  float e = __expf(2.0f * x);
  return 1.0f - 2.0f * __builtin_amdgcn_rcpf(e + 1.0f);
}

// ---------- K1: dec[b,k] = sum_h oh[b,h]*W[k,h] + bias[k] ----------
template <int BF>
__device__ __forceinline__ void k_dec_body(
    const void* oh, const void* W, const void* bias, float* dec) {
  int tid = threadIdx.x;
  int gw = blockIdx.x * 4 + (tid >> 6);   // 8192 waves = 16 b * 512 k
  int lane = tid & 63;
  int k = gw & (HID - 1);
  int b = gw >> 9;
  float wv[8], ov[8];
  load8<BF>(W,  (size_t)k * HID + lane * 8, wv);
  load8<BF>(oh, (size_t)b * HID + lane * 8, ov);
  float acc = 0.0f;
  #pragma unroll
  for (int j = 0; j < 8; ++j) acc += wv[j] * ov[j];
  #pragma unroll
  for (int off = 32; off; off >>= 1) acc += __shfl_xor(acc, off, 64);
  if (lane == 0) dec[b * HID + k] = acc + ld1<BF>(bias, k);
}

__global__ __launch_bounds__(256) void k_dec(
    const void* oh, const void* W, const void* bias, const void* tss,
    float* dec, float* denom) {
  if (blockIdx.x == 0 && threadIdx.x < BATCH) denom[threadIdx.x] = 0.0f;
  if (probe_bf16(tss)) k_dec_body<1>(oh, W, bias, dec);
  else                 k_dec_body<0>(oh, W, bias, dec);
}

// ---------- K2: scores (streams ef), software-pipelined ----------
// 1024 blocks = 16 b * 64 groups (b-fast). Wave owns 16 consecutive s as
// 4 tiles of 4 rows, register-double-buffered: tile t+1's 8 dwordx4 (plus
// ts/mask scalars) are in flight while tile t computes. Explicitly named
// bufA/bufB, hand-scheduled order -> no runtime-indexed reg arrays, and
// the compiler emits counted vmcnt between phases. (256,3): 170-VGPR
// budget for ~116 live regs -> no spill, 12 waves/CU.
template <int BF>
__device__ __forceinline__ void k_scores_body(
    const void* ef, const void* maskp, const void* tssp, const void* vp,
    const float* dec, float* w_buf, float* denom, void* out) {
  int tid = threadIdx.x, lane = tid & 63, wave = tid >> 6;
  int blk = blockIdx.x;
  int b = blk & (BATCH - 1);
  int grp = blk >> 4;
  int sw = grp * SBLK + wave * (NT * SPW);    // wave's first s

  float dv[8], vv[8];
  #pragma unroll
  for (int j = 0; j < 8; ++j) dv[j] = dec[b * HID + lane * 8 + j];
  load8<BF>(vp, lane * 8, vv);

  float evA[SPW][8], evB[SPW][8];
  float tsA[SPW], tsB[SPW], mA[SPW], mB[SPW];
  float wsum = 0.0f;

  auto LOADT = [&](float (&buf)[SPW][8], float (&ts)[SPW], float (&m)[SPW],
                   int t) {
    int s0 = sw + t * SPW;
    #pragma unroll
    for (int i = 0; i < SPW; ++i)
      load8<BF>(ef, ((size_t)(s0 + i) * BATCH + b) * HID + lane * 8, buf[i]);
    #pragma unroll
    for (int i = 0; i < SPW; ++i) {
      ts[i] = ld1<BF>(tssp,  b * SEQ + s0 + i);
      m[i]  = ld1<BF>(maskp, b * SEQ + s0 + i);
    }
  };
  auto COMP = [&](float (&buf)[SPW][8], float (&ts)[SPW], float (&m)[SPW],
                  int t) {
    int s0 = sw + t * SPW;
    float acc[SPW];
    #pragma unroll
    for (int i = 0; i < SPW; ++i) {
      float s = 0.0f;
      #pragma unroll
      for (int j = 0; j < 8; ++j) s += fast_tanh(buf[i][j] + dv[j]) * vv[j];
      acc[i] = s;
    }
    #pragma unroll
    for (int off = 32; off; off >>= 1) {
      #pragma unroll
      for (int i = 0; i < SPW; ++i) acc[i] += __shfl_xor(acc[i], off, 64);
    }
    #pragma unroll
    for (int i = 0; i < SPW; ++i) {
      float p  = __expf(acc[i]);
      float wv = p * m[i] * __builtin_amdgcn_rcpf(ts[i]);
      wsum += wv;
      if (lane == 0) {
        st1<BF>(out, NSS_OFF + b * SEQ + s0 + i, p + ts[i]);
        w_buf[b * SEQ + s0 + i] = wv;
      }
    }
  };

  LOADT(evA, tsA, mA, 0);
  LOADT(evB, tsB, mB, 1);  COMP(evA, tsA, mA, 0);
  LOADT(evA, tsA, mA, 2);  COMP(evB, tsB, mB, 1);
  LOADT(evB, tsB, mB, 3);  COMP(evA, tsA, mA, 2);
                           COMP(evB, tsB, mB, 3);

  __shared__ float wpart[4];
  if (lane == 0) wpart[wave] = wsum;
  __syncthreads();
  if (tid == 0)
    atomicAdd(&denom[b], wpart[0] + wpart[1] + wpart[2] + wpart[3]);
}

__global__ __launch_bounds__(256, 3) void k_scores(
    const void* ef, const void* maskp, const void* tssp, const void* vp,
    const float* dec, float* w_buf, float* denom, void* out) {
  if (probe_bf16(tssp))
    k_scores_body<1>(ef, maskp, tssp, vp, dec, w_buf, denom, out);
  else
    k_scores_body<0>(ef, maskp, tssp, vp, dec, w_buf, denom, out);
}

// ---------- K3: context partials (streams eo), software-pipelined ----------
// Same geometry/pipeline as K2; w prefetched alongside eo rows. a[8]
// accumulates over all 4 tiles -> ONE partial write per block (2 MB total).
template <int BF>
__device__ __forceinline__ void k_ctx_body(
    const void* eo, const float* w_buf, float* partial) {
  int tid = threadIdx.x, lane = tid & 63, wave = tid >> 6;
  int blk = blockIdx.x;
  int b = blk & (BATCH - 1);
  int grp = blk >> 4;
  int sw = grp * SBLK + wave * (NT * SPW);

  float eoA[SPW][8], eoB[SPW][8];
  float wA[SPW], wB[SPW];
  float a[8] = {0,0,0,0,0,0,0,0};

  auto LOADT = [&](float (&buf)[SPW][8], float (&w)[SPW], int t) {
    int s0 = sw + t * SPW;
    #pragma unroll
    for (int i = 0; i < SPW; ++i)
      load8<BF>(eo, ((size_t)(s0 + i) * BATCH + b) * HID + lane * 8, buf[i]);
    #pragma unroll
    for (int i = 0; i < SPW; ++i) w[i] = w_buf[b * SEQ + s0 + i];
  };
  auto COMP = [&](float (&buf)[SPW][8], float (&w)[SPW]) {
    #pragma unroll
    for (int i = 0; i < SPW; ++i)
      #pragma unroll
      for (int j = 0; j < 8; ++j) a[j] += w[i] * buf[i][j];
  };

  LOADT(eoA, wA, 0);
  LOADT(eoB, wB, 1);  COMP(eoA, wA);
  LOADT(eoA, wA, 2);  COMP(eoB, wB);
  LOADT(eoB, wB, 3);  COMP(eoA, wA);
                      COMP(eoB, wB);

  // Cross-wave reduce; lane-consecutive LDS layout -> conflict-free.
  __shared__ float red[3 * 8 * 64];
  if (wave > 0) {
    #pragma unroll
    for (int j = 0; j < 8; ++j) red[((wave - 1) * 8 + j) * 64 + lane] = a[j];
  }
  __syncthreads();
  if (wave == 0) {
    #pragma unroll
    for (int k = 0; k < 3; ++k)
      #pragma unroll
      for (int j = 0; j < 8; ++j) a[j] += red[(k * 8 + j) * 64 + lane];
    float4* p4 = (float4*)(partial + ((size_t)b * NGRP + grp) * HID + lane * 8);
    p4[0] = make_float4(a[0], a[1], a[2], a[3]);
    p4[1] = make_float4(a[4], a[5], a[6], a[7]);
  }
}

__global__ __launch_bounds__(256, 3) void k_ctx(
    const void* eo, const void* tssp, const float* w_buf, float* partial) {
  if (probe_bf16(tssp)) k_ctx_body<1>(eo, w_buf, partial);
  else                  k_ctx_body<0>(eo, w_buf, partial);
}

// ---------- K4: finalize att and ctx ----------
// 512 blocks = 16 b * 32 parts. Per part: 128 s of att + 16 h of ctx.
// 64-group sum split across 16 lanes per h (4 loads each) + 4 shuffle
// stages.
template <int BF>
__device__ __forceinline__ void k_fin_body(
    const float* w_buf, const float* denom, const float* partial, void* out) {
  int b = blockIdx.x >> 5;
  int part = blockIdx.x & 31;
  int t = threadIdx.x;
  float inv_d = __builtin_amdgcn_rcpf(denom[b]);
  if (t < 128) {
    int s = part * 128 + t;
    st1<BF>(out, ATT_OFF + b * SEQ + s, w_buf[b * SEQ + s] * inv_d);
  }
  int hl = t >> 4, cp = t & 15;
  int h = part * 16 + hl;
  float sum = 0.0f;
  #pragma unroll
  for (int c = cp; c < NGRP; c += 16)
    sum += partial[((size_t)b * NGRP + c) * HID + h];
  #pragma unroll
  for (int off = 8; off; off >>= 1) sum += __shfl_xor(sum, off, 64);
  if (cp == 0) st1<BF>(out, b * HID + h, sum * inv_d);
}

__global__ __launch_bounds__(256) void k_finalize(
    const float* w_buf, const float* denom, const float* partial,
    const void* tssp, void* out) {
  if (probe_bf16(tssp)) k_fin_body<1>(w_buf, denom, partial, out);
  else                  k_fin_body<0>(w_buf, denom, partial, out);
}

extern "C" void kernel_launch(void* const* d_in, const int* in_sizes, int n_in,
                              void* d_out, int out_size, void* d_ws, size_t ws_size,
                              hipStream_t stream) {
  const void* oh   = d_in[0];
  const void* eo   = d_in[1];
  const void* ef   = d_in[2];
  const void* mask = d_in[3];
  const void* tss  = d_in[4];
  const void* W    = d_in[5];
  const void* bias = d_in[6];
  const void* v    = d_in[7];

  float* ws      = (float*)d_ws;
  float* dec     = ws;                    // 8192
  float* w_buf   = dec + BATCH * HID;     // 65536
  float* denom   = w_buf + BATCH * SEQ;   // 16
  float* partial = denom + 16;            // 16*64*512 = 524288 (~2.3 MB total)

  k_dec     <<<2048, 256, 0, stream>>>(oh, W, bias, tss, dec, denom);
  k_scores  <<<NSTREAM_BLOCKS, 256, 0, stream>>>(ef, mask, tss, v, dec, w_buf,
                                                 denom, d_out);
  k_ctx     <<<NSTREAM_BLOCKS, 256, 0, stream>>>(eo, tss, w_buf, partial);
  k_finalize<<< 512, 256, 0, stream>>>(w_buf, denom, partial, tss, d_out);
}

// Round 4
// 293.776 us; speedup vs baseline: 1.0973x; 1.0344x over previous
//
#include <hip/hip_runtime.h>
#include <hip/hip_bf16.h>
#include <stdint.h>

#define SEQ 4096
#define BATCH 16
#define HID 512
#define ATT_OFF (BATCH * HID)                 // 8192  elements into d_out
#define NSS_OFF (BATCH * HID + BATCH * SEQ)   // 73728 elements into d_out

// Fused stream geometry: wave owns NT*SPW=8 consecutive s as 4 tiles of 2.
// Block = 4 waves = 32 consecutive s. Both ef and eo rows for a tile are
// register-double-buffered; tile t+1's 8 dwordx4 are in flight while tile
// t computes scores AND accumulates context.
#define SPW 2                                 // s rows per tile per wave
#define NT 4                                  // tiles per wave
#define SBLK (4 * NT * SPW)                   // 32 s per block
#define NGRP (SEQ / SBLK)                     // 128 groups per batch
#define NBLK (BATCH * NGRP)                   // 2048 blocks

typedef unsigned short u16;
typedef unsigned int u32;

__device__ __forceinline__ float bflo(u32 w) { return __uint_as_float(w << 16); }
__device__ __forceinline__ float bfhi(u32 w) { return __uint_as_float(w & 0xffff0000u); }

__device__ __forceinline__ u16 f2bf(float f) {  // round-to-nearest-even
  u32 u = __float_as_uint(f);
  return (u16)((u + 0x7fffu + ((u >> 16) & 1u)) >> 16);
}

// Runtime dtype probe (insurance; prior sessions proved fp32).
__device__ __forceinline__ int probe_bf16(const void* tssp) {
  const u16* t = (const u16*)tssp;
  int ok = 1;
  #pragma unroll
  for (int i = 0; i < 8; i += 2) {
    u16 u = t[i];
    ok &= (u >= 0x3F00 && u <= 0x3FC0) ? 1 : 0;
  }
  return ok;
}

template <int BF>
__device__ __forceinline__ float ld1(const void* p, size_t i) {
  if (BF) return __uint_as_float(((u32)((const u16*)p)[i]) << 16);
  return ((const float*)p)[i];
}

template <int BF>
__device__ __forceinline__ void st1(void* p, size_t i, float v) {
  if (BF) ((u16*)p)[i] = f2bf(v);
  else    ((float*)p)[i] = v;
}

template <int BF>
__device__ __forceinline__ void load8(const void* p, size_t e, float* o) {
  if (BF) {
    uint4 v = *(const uint4*)((const u16*)p + e);
    o[0]=bflo(v.x); o[1]=bfhi(v.x); o[2]=bflo(v.y); o[3]=bfhi(v.y);
    o[4]=bflo(v.z); o[5]=bfhi(v.z); o[6]=bflo(v.w); o[7]=bfhi(v.w);
  } else {
    const float4* f = (const float4*)((const float*)p + e);
    float4 a = f[0], b = f[1];
    o[0]=a.x; o[1]=a.y; o[2]=a.z; o[3]=a.w;
    o[4]=b.x; o[5]=b.y; o[6]=b.z; o[7]=b.w;
  }
}

__device__ __forceinline__ float fast_tanh(float x) {
  float e = __expf(2.0f * x);
  return 1.0f - 2.0f * __builtin_amdgcn_rcpf(e + 1.0f);
}

// ---------- K1: dec[b,k] = sum_h oh[b,h]*W[k,h] + bias[k] ----------
template <int BF>
__device__ __forceinline__ void k_dec_body(
    const void* oh, const void* W, const void* bias, float* dec) {
  int tid = threadIdx.x;
  int gw = blockIdx.x * 4 + (tid >> 6);   // 8192 waves = 16 b * 512 k
  int lane = tid & 63;
  int k = gw & (HID - 1);
  int b = gw >> 9;
  float wv[8], ov[8];
  load8<BF>(W,  (size_t)k * HID + lane * 8, wv);
  load8<BF>(oh, (size_t)b * HID + lane * 8, ov);
  float acc = 0.0f;
  #pragma unroll
  for (int j = 0; j < 8; ++j) acc += wv[j] * ov[j];
  #pragma unroll
  for (int off = 32; off; off >>= 1) acc += __shfl_xor(acc, off, 64);
  if (lane == 0) dec[b * HID + k] = acc + ld1<BF>(bias, k);
}

__global__ __launch_bounds__(256) void k_dec(
    const void* oh, const void* W, const void* bias, const void* tss,
    float* dec, float* denom) {
  if (blockIdx.x == 0 && threadIdx.x < BATCH) denom[threadIdx.x] = 0.0f;
  if (probe_bf16(tss)) k_dec_body<1>(oh, W, bias, dec);
  else                 k_dec_body<0>(oh, W, bias, dec);
}

// ---------- K2: fused scores + context, single pipelined pass ----------
// 2048 blocks = 16 b (fast) * 128 groups. Per tile: load 2 ef rows + 2 eo
// rows (8 dwordx4) + ts/mask; compute tanh-dot, batched butterfly, exp,
// w (all lanes hold w -> ctx FMA needs no broadcast), accumulate a[8].
// A/B-named buffers, hand-unrolled: tile t+1's loads overlap tile t's
// compute; loads from BOTH streams interleave, doubling MLP vs the split
// kernels. One partial write + one denom atomic per block.
template <int BF>
__device__ __forceinline__ void k_str_body(
    const void* ef, const void* eo, const void* maskp, const void* tssp,
    const void* vp, const float* dec, float* w_buf, float* denom,
    float* partial, void* out) {
  int tid = threadIdx.x, lane = tid & 63, wave = tid >> 6;
  int blk = blockIdx.x;
  int b = blk & (BATCH - 1);
  int grp = blk >> 4;
  int sw = grp * SBLK + wave * (NT * SPW);    // wave's first s

  float dv[8], vv[8];
  #pragma unroll
  for (int j = 0; j < 8; ++j) dv[j] = dec[b * HID + lane * 8 + j];
  load8<BF>(vp, lane * 8, vv);

  float evA[SPW][8], evB[SPW][8], eoA[SPW][8], eoB[SPW][8];
  float tsA[SPW], tsB[SPW], mA[SPW], mB[SPW];
  float a[8] = {0,0,0,0,0,0,0,0};
  float wsum = 0.0f;

  auto LOADT = [&](float (&ev)[SPW][8], float (&eov)[SPW][8],
                   float (&ts)[SPW], float (&m)[SPW], int t) {
    int s0 = sw + t * SPW;
    #pragma unroll
    for (int i = 0; i < SPW; ++i) {
      size_t row = ((size_t)(s0 + i) * BATCH + b) * HID + lane * 8;
      load8<BF>(ef, row, ev[i]);
      load8<BF>(eo, row, eov[i]);
    }
    #pragma unroll
    for (int i = 0; i < SPW; ++i) {
      ts[i] = ld1<BF>(tssp,  b * SEQ + s0 + i);
      m[i]  = ld1<BF>(maskp, b * SEQ + s0 + i);
    }
  };
  auto COMPT = [&](float (&ev)[SPW][8], float (&eov)[SPW][8],
                   float (&ts)[SPW], float (&m)[SPW], int t) {
    int s0 = sw + t * SPW;
    float acc[SPW];
    #pragma unroll
    for (int i = 0; i < SPW; ++i) {
      float s = 0.0f;
      #pragma unroll
      for (int j = 0; j < 8; ++j) s += fast_tanh(ev[i][j] + dv[j]) * vv[j];
      acc[i] = s;
    }
    #pragma unroll
    for (int off = 32; off; off >>= 1) {
      #pragma unroll
      for (int i = 0; i < SPW; ++i) acc[i] += __shfl_xor(acc[i], off, 64);
    }
    #pragma unroll
    for (int i = 0; i < SPW; ++i) {
      float p  = __expf(acc[i]);
      float wv = p * m[i] * __builtin_amdgcn_rcpf(ts[i]);
      wsum += wv;
      if (lane == 0) {
        st1<BF>(out, NSS_OFF + b * SEQ + s0 + i, p + ts[i]);
        w_buf[b * SEQ + s0 + i] = wv;
      }
      #pragma unroll
      for (int j = 0; j < 8; ++j) a[j] += wv * eov[i][j];
    }
  };

  LOADT(evA, eoA, tsA, mA, 0);
  LOADT(evB, eoB, tsB, mB, 1);
  COMPT(evA, eoA, tsA, mA, 0);  LOADT(evA, eoA, tsA, mA, 2);
  COMPT(evB, eoB, tsB, mB, 1);  LOADT(evB, eoB, tsB, mB, 3);
  COMPT(evA, eoA, tsA, mA, 2);
  COMPT(evB, eoB, tsB, mB, 3);

  // Cross-wave reduce; lane-consecutive LDS layout -> conflict-free.
  __shared__ float red[3 * 8 * 64];
  __shared__ float wpart[4];
  if (lane == 0) wpart[wave] = wsum;
  if (wave > 0) {
    #pragma unroll
    for (int j = 0; j < 8; ++j) red[((wave - 1) * 8 + j) * 64 + lane] = a[j];
  }
  __syncthreads();
  if (wave == 0) {
    #pragma unroll
    for (int k = 0; k < 3; ++k)
      #pragma unroll
      for (int j = 0; j < 8; ++j) a[j] += red[(k * 8 + j) * 64 + lane];
    float4* p4 = (float4*)(partial + ((size_t)b * NGRP + grp) * HID + lane * 8);
    p4[0] = make_float4(a[0], a[1], a[2], a[3]);
    p4[1] = make_float4(a[4], a[5], a[6], a[7]);
    if (tid == 0)
      atomicAdd(&denom[b], wpart[0] + wpart[1] + wpart[2] + wpart[3]);
  }
}

__global__ __launch_bounds__(256, 3) void k_str(
    const void* ef, const void* eo, const void* maskp, const void* tssp,
    const void* vp, const float* dec, float* w_buf, float* denom,
    float* partial, void* out) {
  if (probe_bf16(tssp))
    k_str_body<1>(ef, eo, maskp, tssp, vp, dec, w_buf, denom, partial, out);
  else
    k_str_body<0>(ef, eo, maskp, tssp, vp, dec, w_buf, denom, partial, out);
}

// ---------- K3: finalize att and ctx ----------
// 512 blocks = 16 b * 32 parts. Per part: 128 s of att + 16 h of ctx.
// 128-group sum split across 16 lanes per h (8 loads each) + 4 shuffle
// stages.
template <int BF>
__device__ __forceinline__ void k_fin_body(
    const float* w_buf, const float* denom, const float* partial, void* out) {
  int b = blockIdx.x >> 5;
  int part = blockIdx.x & 31;
  int t = threadIdx.x;
  float inv_d = __builtin_amdgcn_rcpf(denom[b]);
  if (t < 128) {
    int s = part * 128 + t;
    st1<BF>(out, ATT_OFF + b * SEQ + s, w_buf[b * SEQ + s] * inv_d);
  }
  int hl = t >> 4, cp = t & 15;
  int h = part * 16 + hl;
  float sum = 0.0f;
  #pragma unroll
  for (int c = cp; c < NGRP; c += 16)
    sum += partial[((size_t)b * NGRP + c) * HID + h];
  #pragma unroll
  for (int off = 8; off; off >>= 1) sum += __shfl_xor(sum, off, 64);
  if (cp == 0) st1<BF>(out, b * HID + h, sum * inv_d);
}

__global__ __launch_bounds__(256) void k_finalize(
    const float* w_buf, const float* denom, const float* partial,
    const void* tssp, void* out) {
  if (probe_bf16(tssp)) k_fin_body<1>(w_buf, denom, partial, out);
  else                  k_fin_body<0>(w_buf, denom, partial, out);
}

extern "C" void kernel_launch(void* const* d_in, const int* in_sizes, int n_in,
                              void* d_out, int out_size, void* d_ws, size_t ws_size,
                              hipStream_t stream) {
  const void* oh   = d_in[0];
  const void* eo   = d_in[1];
  const void* ef   = d_in[2];
  const void* mask = d_in[3];
  const void* tss  = d_in[4];
  const void* W    = d_in[5];
  const void* bias = d_in[6];
  const void* v    = d_in[7];

  float* ws      = (float*)d_ws;
  float* dec     = ws;                    // 8192
  float* w_buf   = dec + BATCH * HID;     // 65536
  float* denom   = w_buf + BATCH * SEQ;   // 16
  float* partial = denom + 16;            // 16*128*512 = 1048576 (~4.5 MB total)

  k_dec     <<<2048, 256, 0, stream>>>(oh, W, bias, tss, dec, denom);
  k_str     <<<NBLK, 256, 0, stream>>>(ef, eo, mask, tss, v, dec, w_buf,
                                       denom, partial, d_out);
  k_finalize<<< 512, 256, 0, stream>>>(w_buf, denom, partial, tss, d_out);
}